// Round 1
// baseline (51.203 us; speedup 1.0000x reference)
//
#include <hip/hip_runtime.h>
#include <math.h>

#define FAR_DIST 1e10f
#define EPS 1e-10f

// One 64-lane wave per ray. S=192 -> 3 contiguous samples per lane.
// Exclusive cumprod via lane-local prefix + wave shfl_up scan of lane products.
__global__ __launch_bounds__(256) void render_kernel(
    const float* __restrict__ sigma,   // [N,S]   (S,1 flattened)
    const float* __restrict__ color,   // [N,S,3]
    const float* __restrict__ z_vals,  // [N,S]
    const float* __restrict__ rays,    // [N,6]
    float* __restrict__ rgb,           // [N,3]
    float* __restrict__ weights,       // [N,S]
    int N)
{
    const int S = 192;
    const int wave = threadIdx.x >> 6;
    const int lane = threadIdx.x & 63;
    const int n = blockIdx.x * 4 + wave;
    if (n >= N) return;

    // ray direction norm (broadcast via cache; every lane computes it)
    const float rx = rays[n * 6 + 0];
    const float ry = rays[n * 6 + 1];
    const float rz = rays[n * 6 + 2];
    const float dn = sqrtf(rx * rx + ry * ry + rz * rz);

    const int s0 = lane * 3;                      // 0..189
    const float* zb = z_vals + (size_t)n * S;

    // z values for my 3 samples plus the next one (lane 63's last uses FAR)
    const float z0 = zb[s0 + 0];
    const float z1 = zb[s0 + 1];
    const float z2 = zb[s0 + 2];
    const float z3 = (lane < 63) ? zb[s0 + 3] : 0.0f;

    const float d0 = (z1 - z0) * dn;
    const float d1 = (z2 - z1) * dn;
    const float d2 = (lane < 63) ? (z3 - z2) * dn : FAR_DIST * dn;

    const float* sb = sigma + (size_t)n * S + s0;
    const float sg0 = sb[0];
    const float sg1 = sb[1];
    const float sg2 = sb[2];

    // e = exp(-sigma*dist) = 1 - alpha ; x = 1 - alpha + EPS
    const float e0 = expf(-sg0 * d0);
    const float e1 = expf(-sg1 * d1);
    const float e2 = expf(-sg2 * d2);
    const float x0 = e0 + EPS;
    const float x1 = e1 + EPS;
    const float x2 = e2 + EPS;

    // lane product and wave-wide inclusive scan of products
    const float P = x0 * x1 * x2;
    float scan = P;
    #pragma unroll
    for (int off = 1; off < 64; off <<= 1) {
        const float v = __shfl_up(scan, off, 64);
        if (lane >= off) scan *= v;
    }
    // exclusive prefix product over lanes
    float Texcl = __shfl_up(scan, 1, 64);
    if (lane == 0) Texcl = 1.0f;

    // weights for my 3 samples (exclusive cumprod within lane too)
    const float a0 = 1.0f - e0;
    const float a1 = 1.0f - e1;
    const float a2 = 1.0f - e2;
    const float T0 = Texcl;
    const float T1 = Texcl * x0;
    const float T2 = T1 * x1;
    const float w0 = a0 * T0;
    const float w1 = a1 * T1;
    const float w2 = a2 * T2;

    float* wb = weights + (size_t)n * S + s0;
    wb[0] = w0;
    wb[1] = w1;
    wb[2] = w2;

    // rgb accumulation
    const float* cb = color + ((size_t)n * S + s0) * 3;
    float r = w0 * cb[0] + w1 * cb[3] + w2 * cb[6];
    float g = w0 * cb[1] + w1 * cb[4] + w2 * cb[7];
    float b = w0 * cb[2] + w1 * cb[5] + w2 * cb[8];

    // wave reduce
    #pragma unroll
    for (int off = 32; off >= 1; off >>= 1) {
        r += __shfl_xor(r, off, 64);
        g += __shfl_xor(g, off, 64);
        b += __shfl_xor(b, off, 64);
    }
    if (lane == 0) {
        rgb[n * 3 + 0] = r;
        rgb[n * 3 + 1] = g;
        rgb[n * 3 + 2] = b;
    }
}

extern "C" void kernel_launch(void* const* d_in, const int* in_sizes, int n_in,
                              void* d_out, int out_size, void* d_ws, size_t ws_size,
                              hipStream_t stream) {
    const float* sigma  = (const float*)d_in[0];  // [N,S,1]
    const float* color  = (const float*)d_in[1];  // [N,S,3]
    const float* z_vals = (const float*)d_in[2];  // [N,S]
    const float* rays   = (const float*)d_in[3];  // [N,6]

    const int N = in_sizes[3] / 6;                // 65536
    // output: rgb [N,3] then weights [N,S,1]
    float* rgb     = (float*)d_out;
    float* weights = (float*)d_out + (size_t)N * 3;

    const int blocks = (N + 3) / 4;               // 4 rays (waves) per 256-thread block
    render_kernel<<<blocks, 256, 0, stream>>>(sigma, color, z_vals, rays,
                                              rgb, weights, N);
}

// Round 3
// 47.813 us; speedup vs baseline: 1.0709x; 1.0709x over previous
//
#include <hip/hip_runtime.h>
#include <math.h>

#define FAR_DIST 1e10f
#define EPS 1e-10f

typedef float f32x4 __attribute__((ext_vector_type(4)));

// One 64-lane wave per ray; lanes 0..47 each own 4 contiguous samples
// (S=192 = 48 lanes x 4). 16B vector loads/stores, wave prefix-product scan.
__global__ __launch_bounds__(256) void render_kernel(
    const float* __restrict__ sigma,   // [N,S]
    const float* __restrict__ color,   // [N,S,3]
    const float* __restrict__ z_vals,  // [N,S]
    const float* __restrict__ rays,    // [N,6]
    float* __restrict__ rgb,           // [N,3]
    float* __restrict__ weights,       // [N,S]
    int N)
{
    const int S = 192;
    const int wave = threadIdx.x >> 6;
    const int lane = threadIdx.x & 63;
    const int n = blockIdx.x * 4 + wave;
    if (n >= N) return;

    const bool active = (lane < 48);
    const int s0 = lane * 4;

    // ray direction norm (broadcast load)
    const float rx = rays[n * 6 + 0];
    const float ry = rays[n * 6 + 1];
    const float rz = rays[n * 6 + 2];
    const float dn = sqrtf(rx * rx + ry * ry + rz * rz);

    const float* zb = z_vals + (size_t)n * S;
    f32x4 z4 = (f32x4)(0.f);
    if (active) z4 = *(const f32x4*)(zb + s0);

    // next lane's first z (for my last interval); lane 47 uses FAR
    const float znext = __shfl_down(z4.x, 1, 64);

    const float d0 = (z4.y - z4.x) * dn;
    const float d1 = (z4.z - z4.y) * dn;
    const float d2 = (z4.w - z4.z) * dn;
    const float d3 = (lane == 47) ? FAR_DIST * dn : (znext - z4.w) * dn;

    f32x4 sg = (f32x4)(0.f);
    if (active) sg = *(const f32x4*)(sigma + (size_t)n * S + s0);

    // e = exp(-sigma*dist) = 1 - alpha ; x = e + EPS
    const float e0 = expf(-sg.x * d0);
    const float e1 = expf(-sg.y * d1);
    const float e2 = expf(-sg.z * d2);
    const float e3 = expf(-sg.w * d3);
    const float x0 = e0 + EPS;
    const float x1 = e1 + EPS;
    const float x2 = e2 + EPS;
    const float x3 = e3 + EPS;

    // lane product; inactive lanes contribute identity
    float P = active ? (x0 * x1) * (x2 * x3) : 1.0f;

    // wave-wide inclusive scan of lane products
    float scan = P;
    #pragma unroll
    for (int off = 1; off < 64; off <<= 1) {
        const float v = __shfl_up(scan, off, 64);
        if (lane >= off) scan *= v;
    }
    float Texcl = __shfl_up(scan, 1, 64);
    if (lane == 0) Texcl = 1.0f;

    // per-sample transmittance and weights
    const float T0 = Texcl;
    const float T1 = T0 * x0;
    const float T2 = T1 * x1;
    const float T3 = T2 * x2;
    const float w0 = (1.0f - e0) * T0;
    const float w1 = (1.0f - e1) * T1;
    const float w2 = (1.0f - e2) * T2;
    const float w3 = (1.0f - e3) * T3;

    if (active) {
        f32x4 w4;
        w4.x = w0; w4.y = w1; w4.z = w2; w4.w = w3;
        __builtin_nontemporal_store(w4, (f32x4*)(weights + (size_t)n * S + s0));
    }

    // rgb accumulation: 12 colors per active lane as 3 x 16B vectors
    float r = 0.f, g = 0.f, b = 0.f;
    if (active) {
        const float* cb = color + ((size_t)n * S + s0) * 3;
        const f32x4 c0 = *(const f32x4*)(cb + 0);   // s0.rgb, s1.r
        const f32x4 c1 = *(const f32x4*)(cb + 4);   // s1.gb, s2.rg
        const f32x4 c2 = *(const f32x4*)(cb + 8);   // s2.b, s3.rgb
        r = w0 * c0.x + w1 * c0.w + w2 * c1.z + w3 * c2.y;
        g = w0 * c0.y + w1 * c1.x + w2 * c1.w + w3 * c2.z;
        b = w0 * c0.z + w1 * c1.y + w2 * c2.x + w3 * c2.w;
    }

    // wave reduce (all 64 lanes participate; inactive contribute 0)
    #pragma unroll
    for (int off = 32; off >= 1; off >>= 1) {
        r += __shfl_xor(r, off, 64);
        g += __shfl_xor(g, off, 64);
        b += __shfl_xor(b, off, 64);
    }
    if (lane == 0) {
        __builtin_nontemporal_store(r, rgb + n * 3 + 0);
        __builtin_nontemporal_store(g, rgb + n * 3 + 1);
        __builtin_nontemporal_store(b, rgb + n * 3 + 2);
    }
}

extern "C" void kernel_launch(void* const* d_in, const int* in_sizes, int n_in,
                              void* d_out, int out_size, void* d_ws, size_t ws_size,
                              hipStream_t stream) {
    const float* sigma  = (const float*)d_in[0];  // [N,S,1]
    const float* color  = (const float*)d_in[1];  // [N,S,3]
    const float* z_vals = (const float*)d_in[2];  // [N,S]
    const float* rays   = (const float*)d_in[3];  // [N,6]

    const int N = in_sizes[3] / 6;                // 65536
    float* rgb     = (float*)d_out;               // [N,3]
    float* weights = (float*)d_out + (size_t)N * 3;  // [N,S,1]

    const int blocks = (N + 3) / 4;               // 4 rays (waves) per 256-thread block
    render_kernel<<<blocks, 256, 0, stream>>>(sigma, color, z_vals, rays,
                                              rgb, weights, N);
}